// Round 2
// baseline (683.061 us; speedup 1.0000x reference)
//
#include <hip/hip_runtime.h>
#include <hip/hip_bf16.h>

typedef __attribute__((ext_vector_type(8))) short bf16x8_t;
typedef __attribute__((ext_vector_type(4))) float f32x4_t;

#define LROW 40  // LDS row stride in shorts (80 B: 16B-aligned)

__device__ inline unsigned short f2bf(float f) {
    __hip_bfloat16 h = __float2bfloat16(f);
    return *reinterpret_cast<unsigned short*>(&h);
}

// ---------------- convert x fp32 -> bf16 ----------------
__global__ __launch_bounds__(256) void cvt_x_kernel(
    const float* __restrict__ x, ushort* __restrict__ xb)
{
    size_t i = ((size_t)blockIdx.x * 256 + threadIdx.x) * 4;
    float4 v = *(const float4*)(x + i);
    ushort4 o;
    o.x = f2bf(v.x); o.y = f2bf(v.y); o.z = f2bf(v.z); o.w = f2bf(v.w);
    *(ushort4*)(xb + i) = o;
}

// ---------- transpose+convert 1024x1024 fp32 matrices (16 of them) -> bf16 ----------
__global__ __launch_bounds__(256) void transpose_kernel(
    const float* __restrict__ Wup, const float* __restrict__ Wdn,
    ushort* __restrict__ WtUp, ushort* __restrict__ WtDn)
{
    int z = blockIdx.z;
    const float* src = (z < 8) ? (Wup + ((size_t)z << 20)) : (Wdn + ((size_t)(z - 8) << 20));
    ushort* dst      = (z < 8) ? (WtUp + ((size_t)z << 20)) : (WtDn + ((size_t)(z - 8) << 20));
    __shared__ float tile[64][65];
    int x0 = blockIdx.x * 64, y0 = blockIdx.y * 64;
    int row = threadIdx.x >> 4, colq = threadIdx.x & 15;
#pragma unroll
    for (int it = 0; it < 4; it++) {
        int r = row + it * 16;
        float4 v = *(const float4*)(src + (size_t)(y0 + r) * 1024 + x0 + colq * 4);
        tile[r][colq * 4 + 0] = v.x; tile[r][colq * 4 + 1] = v.y;
        tile[r][colq * 4 + 2] = v.z; tile[r][colq * 4 + 3] = v.w;
    }
    __syncthreads();
#pragma unroll
    for (int it = 0; it < 4; it++) {
        int r = row + it * 16;
        ushort4 o;
        o.x = f2bf(tile[colq * 4 + 0][r]); o.y = f2bf(tile[colq * 4 + 1][r]);
        o.z = f2bf(tile[colq * 4 + 2][r]); o.w = f2bf(tile[colq * 4 + 3][r]);
        *(ushort4*)(dst + (size_t)(x0 + r) * 1024 + y0 + colq * 4) = o;
    }
}

// ---------------- router: logits, top-2, softmax, counts ----------------
__global__ __launch_bounds__(256) void router_kernel(
    const float* __restrict__ x, const float* __restrict__ rw,
    const float* __restrict__ rb,
    int* cnt, float* sum_w, int2* tok_e, float2* tok_w)
{
    int wave = threadIdx.x >> 6, lane = threadIdx.x & 63;
    int t = blockIdx.x * 4 + wave;
    float xv[16];
#pragma unroll
    for (int i = 0; i < 16; i++) xv[i] = x[(size_t)t * 1024 + lane + i * 64];
    float logit[8];
#pragma unroll
    for (int e = 0; e < 8; e++) {
        float s = 0.f;
#pragma unroll
        for (int i = 0; i < 16; i++) s += xv[i] * rw[e * 1024 + lane + i * 64];
#pragma unroll
        for (int m = 32; m >= 1; m >>= 1) s += __shfl_xor(s, m, 64);
        logit[e] = s + rb[e];
    }
    // top-2, ties -> lowest index (matches jax.lax.top_k)
    int i0 = 0;
#pragma unroll
    for (int e = 1; e < 8; e++) if (logit[e] > logit[i0]) i0 = e;
    int i1 = -1;
#pragma unroll
    for (int e = 0; e < 8; e++) if (e != i0 && (i1 < 0 || logit[e] > logit[i1])) i1 = e;
    float ev = expf(logit[i1] - logit[i0]);
    float s = 1.f + ev;
    float w0 = 1.f / s, w1 = ev / s;
    if (lane == 0) {
        atomicAdd(&cnt[i0], 1); atomicAdd(&cnt[i1], 1);
        atomicAdd(&sum_w[i0], w0); atomicAdd(&sum_w[i1], w1);
        tok_e[t] = make_int2(i0, i1);
        tok_w[t] = make_float2(w0, w1);
    }
}

// ---------------- tiny scan: offsets + aux loss ----------------
__global__ void scan_kernel(const int* cnt, const float* sum_w, int* off,
                            float* aux_out)
{
    if (threadIdx.x == 0) {
        int o = 0; float aux = 0.f;
        for (int e = 0; e < 8; e++) {
            off[e] = o; o += cnt[e];
            aux += (float)cnt[e] * sum_w[e];
        }
        aux *= 8.0f / (8192.0f * 8192.0f);
        *aux_out = aux;
    }
}

// ---------------- slot assignment ----------------
__global__ __launch_bounds__(256) void assign_kernel(
    const int2* __restrict__ tok_e, const float2* __restrict__ tok_w,
    const int* __restrict__ off, int* c2, int* pair_token, float* pair_w)
{
    int t = blockIdx.x * 256 + threadIdx.x;
    int2 e = tok_e[t]; float2 w = tok_w[t];
    int s0 = off[e.x] + atomicAdd(&c2[e.x], 1);
    pair_token[s0] = t; pair_w[s0] = w.x;
    int s1 = off[e.y] + atomicAdd(&c2[e.y], 1);
    pair_token[s1] = t; pair_w[s1] = w.y;
}

// ---------------- up GEMM: H = gelu(Xg @ Wup + bup) * w ----------------
__global__ __launch_bounds__(256) void up_gemm(
    const ushort* __restrict__ xb, const ushort* __restrict__ WtUp,
    const float* __restrict__ bup,
    const int* __restrict__ cnt, const int* __restrict__ off,
    const int* __restrict__ pair_token, const float* __restrict__ pair_w,
    ushort* __restrict__ Hbuf)
{
    int e = blockIdx.y >> 7;
    int mt = blockIdx.y & 127;
    int M = cnt[e];
    if (mt * 64 >= M) return;
    int rowBase = off[e] + mt * 64;
    int colBase = blockIdx.x * 64;
    const ushort* Bsrc = WtUp + ((size_t)e << 20);  // [h][d]

    __shared__ ushort As[64 * LROW];
    __shared__ ushort Bs[64 * LROW];

    int tid = threadIdx.x;
    int wave = tid >> 6, lane = tid & 63;
    int q = lane >> 4, r = lane & 15;
    int sRow = tid >> 2, sChunk = tid & 3;

    const ushort* aSrc = nullptr;
    if (mt * 64 + sRow < M) {
        int tok = pair_token[rowBase + sRow];
        aSrc = xb + (size_t)tok * 1024 + sChunk * 8;
    }
    const ushort* bSrc = Bsrc + (size_t)(colBase + sRow) * 1024 + sChunk * 8;
    ushort* aDst = &As[sRow * LROW + sChunk * 8];
    ushort* bDst = &Bs[sRow * LROW + sChunk * 8];

    f32x4_t acc[4];
#pragma unroll
    for (int j = 0; j < 4; j++) { acc[j][0] = 0.f; acc[j][1] = 0.f; acc[j][2] = 0.f; acc[j][3] = 0.f; }

    for (int kk = 0; kk < 1024; kk += 32) {
        uint4 av = {0u, 0u, 0u, 0u};
        if (aSrc) av = *(const uint4*)(aSrc + kk);
        uint4 bv = *(const uint4*)(bSrc + kk);
        *(uint4*)aDst = av;
        *(uint4*)bDst = bv;
        __syncthreads();
        bf16x8_t af = *(const bf16x8_t*)(&As[(wave * 16 + r) * LROW + q * 8]);
#pragma unroll
        for (int j = 0; j < 4; j++) {
            bf16x8_t bv2 = *(const bf16x8_t*)(&Bs[(j * 16 + r) * LROW + q * 8]);
            acc[j] = __builtin_amdgcn_mfma_f32_16x16x32_bf16(af, bv2, acc[j], 0, 0, 0);
        }
        __syncthreads();
    }

    int rl0 = wave * 16 + q * 4;
#pragma unroll
    for (int j = 0; j < 4; j++) {
        int col = colBase + j * 16 + r;
        float bias = bup[e * 1024 + col];
#pragma unroll
        for (int i = 0; i < 4; i++) {
            int rl = rl0 + i;
            if (mt * 64 + rl < M) {
                float h = acc[j][i] + bias;
                float g = 0.5f * h * (1.0f + erff(h * 0.70710678118654752f));
                float wgt = pair_w[rowBase + rl];
                Hbuf[(size_t)(rowBase + rl) * 1024 + col] = f2bf(g * wgt);
            }
        }
    }
}

// ---------------- down GEMM: acc[token] += H @ Wdn ----------------
__global__ __launch_bounds__(256) void down_gemm(
    const ushort* __restrict__ Hbuf, const ushort* __restrict__ WtDn,
    const int* __restrict__ cnt, const int* __restrict__ off,
    const int* __restrict__ pair_token,
    float* __restrict__ accOut)
{
    int e = blockIdx.y >> 7;
    int mt = blockIdx.y & 127;
    int M = cnt[e];
    if (mt * 64 >= M) return;
    int rowBase = off[e] + mt * 64;
    int colBase = blockIdx.x * 64;
    const ushort* Bsrc = WtDn + ((size_t)e << 20);  // [d][h]

    __shared__ ushort As[64 * LROW];
    __shared__ ushort Bs[64 * LROW];

    int tid = threadIdx.x;
    int wave = tid >> 6, lane = tid & 63;
    int q = lane >> 4, r = lane & 15;
    int sRow = tid >> 2, sChunk = tid & 3;

    const ushort* aSrc = nullptr;
    if (mt * 64 + sRow < M) aSrc = Hbuf + (size_t)(rowBase + sRow) * 1024 + sChunk * 8;
    const ushort* bSrc = Bsrc + (size_t)(colBase + sRow) * 1024 + sChunk * 8;
    ushort* aDst = &As[sRow * LROW + sChunk * 8];
    ushort* bDst = &Bs[sRow * LROW + sChunk * 8];

    f32x4_t acc[4];
#pragma unroll
    for (int j = 0; j < 4; j++) { acc[j][0] = 0.f; acc[j][1] = 0.f; acc[j][2] = 0.f; acc[j][3] = 0.f; }

    for (int kk = 0; kk < 1024; kk += 32) {
        uint4 av = {0u, 0u, 0u, 0u};
        if (aSrc) av = *(const uint4*)(aSrc + kk);
        uint4 bv = *(const uint4*)(bSrc + kk);
        *(uint4*)aDst = av;
        *(uint4*)bDst = bv;
        __syncthreads();
        bf16x8_t af = *(const bf16x8_t*)(&As[(wave * 16 + r) * LROW + q * 8]);
#pragma unroll
        for (int j = 0; j < 4; j++) {
            bf16x8_t bv2 = *(const bf16x8_t*)(&Bs[(j * 16 + r) * LROW + q * 8]);
            acc[j] = __builtin_amdgcn_mfma_f32_16x16x32_bf16(af, bv2, acc[j], 0, 0, 0);
        }
        __syncthreads();
    }

    int rl0 = wave * 16 + q * 4;
#pragma unroll
    for (int j = 0; j < 4; j++) {
        int col = colBase + j * 16 + r;
#pragma unroll
        for (int i = 0; i < 4; i++) {
            int rl = rl0 + i;
            if (mt * 64 + rl < M) {
                int tok = pair_token[rowBase + rl];
                atomicAdd(&accOut[(size_t)tok * 1024 + col], acc[j][i]);
            }
        }
    }
}

// ---------------- finalize: out = acc + w0*bdn[e0] + w1*bdn[e1] ----------------
__global__ __launch_bounds__(256) void finalize_kernel(
    const float* __restrict__ accOut, const int2* __restrict__ tok_e,
    const float2* __restrict__ tok_w, const float* __restrict__ bdn,
    float* __restrict__ out)
{
    int t = blockIdx.x;
    int2 e = tok_e[t]; float2 w = tok_w[t];
    int c = threadIdx.x * 4;
    float4 a = *(const float4*)(accOut + (size_t)t * 1024 + c);
    float4 b0 = *(const float4*)(bdn + (size_t)e.x * 1024 + c);
    float4 b1 = *(const float4*)(bdn + (size_t)e.y * 1024 + c);
    float4 o;
    o.x = a.x + w.x * b0.x + w.y * b1.x;
    o.y = a.y + w.x * b0.y + w.y * b1.y;
    o.z = a.z + w.x * b0.z + w.y * b1.z;
    o.w = a.w + w.x * b0.w + w.y * b1.w;
    *(float4*)(out + (size_t)t * 1024 + c) = o;
}

extern "C" void kernel_launch(void* const* d_in, const int* in_sizes, int n_in,
                              void* d_out, int out_size, void* d_ws, size_t ws_size,
                              hipStream_t stream) {
    const float* x   = (const float*)d_in[0];
    const float* rw  = (const float*)d_in[1];
    const float* rb  = (const float*)d_in[2];
    const float* Wup = (const float*)d_in[3];
    const float* bup = (const float*)d_in[4];
    const float* Wdn = (const float*)d_in[5];
    const float* bdn = (const float*)d_in[6];
    float* out = (float*)d_out;

    char* ws = (char*)d_ws;
    int*    cnt   = (int*)(ws + 0);     // 8 ints
    int*    c2    = (int*)(ws + 32);    // 8 ints
    float*  sum_w = (float*)(ws + 64);  // 8 floats
    int*    off   = (int*)(ws + 96);    // 8 ints
    int2*   tok_e = (int2*)(ws + 256);                  // 8192 * 8  = 64 KB
    float2* tok_w = (float2*)(ws + 256 + 65536);        // 64 KB
    int*    pair_token = (int*)(ws + 256 + 131072);     // 16384 * 4 = 64 KB
    float*  pair_w     = (float*)(ws + 256 + 196608);   // 64 KB
    char* big = ws + 262400;
    ushort* Hbuf   = (ushort*)big;                        // 16384*1024*2 = 33554432
    float*  accOut = (float*)(big + 33554432);            // 8192*1024*4  = 33554432
    ushort* WtUp   = (ushort*)(big + 67108864);           // 16777216
    ushort* WtDn   = (ushort*)(big + 83886080);           // 16777216
    ushort* xb     = (ushort*)(big + 100663296);          // 8192*1024*2 = 16777216

    hipMemsetAsync(ws, 0, 128, stream);
    hipMemsetAsync(accOut, 0, (size_t)8192 * 1024 * sizeof(float), stream);

    cvt_x_kernel<<<8192, 256, 0, stream>>>(x, xb);
    transpose_kernel<<<dim3(16, 16, 16), 256, 0, stream>>>(Wup, Wdn, WtUp, WtDn);
    router_kernel<<<2048, 256, 0, stream>>>(x, rw, rb, cnt, sum_w, tok_e, tok_w);
    scan_kernel<<<1, 64, 0, stream>>>(cnt, sum_w, off, out + 8388608);
    assign_kernel<<<32, 256, 0, stream>>>(tok_e, tok_w, off, c2, pair_token, pair_w);
    up_gemm<<<dim3(16, 1024), 256, 0, stream>>>(
        xb, WtUp, bup, cnt, off, pair_token, pair_w, Hbuf);
    down_gemm<<<dim3(16, 1024), 256, 0, stream>>>(
        Hbuf, WtDn, cnt, off, pair_token, accOut);
    finalize_kernel<<<8192, 256, 0, stream>>>(accOut, tok_e, tok_w, bdn, out);
}

// Round 3
// 404.208 us; speedup vs baseline: 1.6899x; 1.6899x over previous
//
#include <hip/hip_runtime.h>
#include <hip/hip_bf16.h>

typedef __attribute__((ext_vector_type(8))) short bf16x8_t;
typedef __attribute__((ext_vector_type(4))) float f32x4_t;

#define LROW 40  // LDS row stride in shorts (80 B: 16B-aligned)

__device__ inline unsigned short f2bf(float f) {
    __hip_bfloat16 h = __float2bfloat16(f);
    return *reinterpret_cast<unsigned short*>(&h);
}

// ---------------- convert x fp32 -> bf16 ----------------
__global__ __launch_bounds__(256) void cvt_x_kernel(
    const float* __restrict__ x, ushort* __restrict__ xb)
{
    size_t i = ((size_t)blockIdx.x * 256 + threadIdx.x) * 4;
    float4 v = *(const float4*)(x + i);
    ushort4 o;
    o.x = f2bf(v.x); o.y = f2bf(v.y); o.z = f2bf(v.z); o.w = f2bf(v.w);
    *(ushort4*)(xb + i) = o;
}

// ---------- transpose+convert 1024x1024 fp32 matrices (16 of them) -> bf16 ----------
__global__ __launch_bounds__(256) void transpose_kernel(
    const float* __restrict__ Wup, const float* __restrict__ Wdn,
    ushort* __restrict__ WtUp, ushort* __restrict__ WtDn)
{
    int z = blockIdx.z;
    const float* src = (z < 8) ? (Wup + ((size_t)z << 20)) : (Wdn + ((size_t)(z - 8) << 20));
    ushort* dst      = (z < 8) ? (WtUp + ((size_t)z << 20)) : (WtDn + ((size_t)(z - 8) << 20));
    __shared__ float tile[64][65];
    int x0 = blockIdx.x * 64, y0 = blockIdx.y * 64;
    int row = threadIdx.x >> 4, colq = threadIdx.x & 15;
#pragma unroll
    for (int it = 0; it < 4; it++) {
        int r = row + it * 16;
        float4 v = *(const float4*)(src + (size_t)(y0 + r) * 1024 + x0 + colq * 4);
        tile[r][colq * 4 + 0] = v.x; tile[r][colq * 4 + 1] = v.y;
        tile[r][colq * 4 + 2] = v.z; tile[r][colq * 4 + 3] = v.w;
    }
    __syncthreads();
#pragma unroll
    for (int it = 0; it < 4; it++) {
        int r = row + it * 16;
        ushort4 o;
        o.x = f2bf(tile[colq * 4 + 0][r]); o.y = f2bf(tile[colq * 4 + 1][r]);
        o.z = f2bf(tile[colq * 4 + 2][r]); o.w = f2bf(tile[colq * 4 + 3][r]);
        *(ushort4*)(dst + (size_t)(x0 + r) * 1024 + y0 + colq * 4) = o;
    }
}

// ---------------- router: logits, top-2, softmax. NO atomics. ----------------
__global__ __launch_bounds__(256) void router_kernel(
    const float* __restrict__ x, const float* __restrict__ rw,
    const float* __restrict__ rb,
    int2* __restrict__ tok_e, float2* __restrict__ tok_w)
{
    int wave = threadIdx.x >> 6, lane = threadIdx.x & 63;
    int t = blockIdx.x * 4 + wave;
    float4 xv[4];
#pragma unroll
    for (int i = 0; i < 4; i++)
        xv[i] = *(const float4*)(x + (size_t)t * 1024 + i * 256 + lane * 4);
    float logit[8];
#pragma unroll
    for (int e = 0; e < 8; e++) {
        float s = 0.f;
#pragma unroll
        for (int i = 0; i < 4; i++) {
            float4 wv = *(const float4*)(rw + e * 1024 + i * 256 + lane * 4);
            s += xv[i].x * wv.x + xv[i].y * wv.y + xv[i].z * wv.z + xv[i].w * wv.w;
        }
#pragma unroll
        for (int m = 32; m >= 1; m >>= 1) s += __shfl_xor(s, m, 64);
        logit[e] = s + rb[e];
    }
    // top-2, ties -> lowest index (matches jax.lax.top_k)
    int i0 = 0;
#pragma unroll
    for (int e = 1; e < 8; e++) if (logit[e] > logit[i0]) i0 = e;
    int i1 = -1;
#pragma unroll
    for (int e = 0; e < 8; e++) if (e != i0 && (i1 < 0 || logit[e] > logit[i1])) i1 = e;
    float ev = expf(logit[i1] - logit[i0]);
    float s = 1.f + ev;
    if (lane == 0) {
        tok_e[t] = make_int2(i0, i1);
        tok_w[t] = make_float2(1.f / s, ev / s);
    }
}

// ---------------- per-block histograms (counts + weight sums) ----------------
__global__ __launch_bounds__(256) void count_kernel(
    const int2* __restrict__ tok_e, const float2* __restrict__ tok_w,
    int* __restrict__ blockCnt, float* __restrict__ blockSum)
{
    __shared__ int lcnt[8];
    __shared__ float lsum[8];
    int tid = threadIdx.x;
    if (tid < 8) { lcnt[tid] = 0; lsum[tid] = 0.f; }
    __syncthreads();
    int t = blockIdx.x * 256 + tid;
    int2 e = tok_e[t]; float2 w = tok_w[t];
    atomicAdd(&lcnt[e.x], 1); atomicAdd(&lsum[e.x], w.x);
    atomicAdd(&lcnt[e.y], 1); atomicAdd(&lsum[e.y], w.y);
    __syncthreads();
    if (tid < 8) {
        blockCnt[blockIdx.x * 8 + tid] = lcnt[tid];
        blockSum[blockIdx.x * 8 + tid] = lsum[tid];
    }
}

// ---------------- scan: expert offsets, per-block bases, aux loss ----------------
__global__ void scan_kernel(const int* __restrict__ blockCnt,
                            const float* __restrict__ blockSum,
                            int* __restrict__ cnt, int* __restrict__ off,
                            int* __restrict__ base, float* aux_out)
{
    if (threadIdx.x == 0) {
        int tot[8]; float sw[8];
        for (int e = 0; e < 8; e++) { tot[e] = 0; sw[e] = 0.f; }
        for (int b = 0; b < 32; b++)
            for (int e = 0; e < 8; e++) { tot[e] += blockCnt[b * 8 + e]; sw[e] += blockSum[b * 8 + e]; }
        int o = 0; float aux = 0.f;
        for (int e = 0; e < 8; e++) {
            cnt[e] = tot[e]; off[e] = o;
            aux += (float)tot[e] * sw[e];
            int run = o;
            for (int b = 0; b < 32; b++) { base[b * 8 + e] = run; run += blockCnt[b * 8 + e]; }
            o += tot[e];
        }
        aux *= 8.0f / (8192.0f * 8192.0f);
        *aux_out = aux;
    }
}

// ---------------- slot assignment: LDS-atomic local ranks ----------------
__global__ __launch_bounds__(256) void assign_kernel(
    const int2* __restrict__ tok_e, const float2* __restrict__ tok_w,
    const int* __restrict__ base, int* __restrict__ pair_token,
    float* __restrict__ pair_w)
{
    __shared__ int lcnt[8];
    int tid = threadIdx.x;
    if (tid < 8) lcnt[tid] = 0;
    __syncthreads();
    int t = blockIdx.x * 256 + tid;
    int2 e = tok_e[t]; float2 w = tok_w[t];
    int r0 = atomicAdd(&lcnt[e.x], 1);
    int r1 = atomicAdd(&lcnt[e.y], 1);
    int s0 = base[blockIdx.x * 8 + e.x] + r0;
    int s1 = base[blockIdx.x * 8 + e.y] + r1;
    pair_token[s0] = t; pair_w[s0] = w.x;
    pair_token[s1] = t; pair_w[s1] = w.y;
}

// ---------------- up GEMM: H = gelu(Xg @ Wup + bup) * w ----------------
__global__ __launch_bounds__(256) void up_gemm(
    const ushort* __restrict__ xb, const ushort* __restrict__ WtUp,
    const float* __restrict__ bup,
    const int* __restrict__ cnt, const int* __restrict__ off,
    const int* __restrict__ pair_token, const float* __restrict__ pair_w,
    ushort* __restrict__ Hbuf)
{
    int e = blockIdx.y >> 7;
    int mt = blockIdx.y & 127;
    int M = cnt[e];
    if (mt * 64 >= M) return;
    int rowBase = off[e] + mt * 64;
    int colBase = blockIdx.x * 64;
    const ushort* Bsrc = WtUp + ((size_t)e << 20);  // [h][d]

    __shared__ ushort As[64 * LROW];
    __shared__ ushort Bs[64 * LROW];

    int tid = threadIdx.x;
    int wave = tid >> 6, lane = tid & 63;
    int q = lane >> 4, r = lane & 15;
    int sRow = tid >> 2, sChunk = tid & 3;

    const ushort* aSrc = nullptr;
    if (mt * 64 + sRow < M) {
        int tok = pair_token[rowBase + sRow];
        aSrc = xb + (size_t)tok * 1024 + sChunk * 8;
    }
    const ushort* bSrc = Bsrc + (size_t)(colBase + sRow) * 1024 + sChunk * 8;
    ushort* aDst = &As[sRow * LROW + sChunk * 8];
    ushort* bDst = &Bs[sRow * LROW + sChunk * 8];

    f32x4_t acc[4];
#pragma unroll
    for (int j = 0; j < 4; j++) { acc[j][0] = 0.f; acc[j][1] = 0.f; acc[j][2] = 0.f; acc[j][3] = 0.f; }

    for (int kk = 0; kk < 1024; kk += 32) {
        uint4 av = {0u, 0u, 0u, 0u};
        if (aSrc) av = *(const uint4*)(aSrc + kk);
        uint4 bv = *(const uint4*)(bSrc + kk);
        *(uint4*)aDst = av;
        *(uint4*)bDst = bv;
        __syncthreads();
        bf16x8_t af = *(const bf16x8_t*)(&As[(wave * 16 + r) * LROW + q * 8]);
#pragma unroll
        for (int j = 0; j < 4; j++) {
            bf16x8_t bv2 = *(const bf16x8_t*)(&Bs[(j * 16 + r) * LROW + q * 8]);
            acc[j] = __builtin_amdgcn_mfma_f32_16x16x32_bf16(af, bv2, acc[j], 0, 0, 0);
        }
        __syncthreads();
    }

    int rl0 = wave * 16 + q * 4;
#pragma unroll
    for (int j = 0; j < 4; j++) {
        int col = colBase + j * 16 + r;
        float bias = bup[e * 1024 + col];
#pragma unroll
        for (int i = 0; i < 4; i++) {
            int rl = rl0 + i;
            if (mt * 64 + rl < M) {
                float h = acc[j][i] + bias;
                float g = 0.5f * h * (1.0f + erff(h * 0.70710678118654752f));
                float wgt = pair_w[rowBase + rl];
                Hbuf[(size_t)(rowBase + rl) * 1024 + col] = f2bf(g * wgt);
            }
        }
    }
}

// ---------------- down GEMM: acc[token] += H @ Wdn ----------------
__global__ __launch_bounds__(256) void down_gemm(
    const ushort* __restrict__ Hbuf, const ushort* __restrict__ WtDn,
    const int* __restrict__ cnt, const int* __restrict__ off,
    const int* __restrict__ pair_token,
    float* __restrict__ accOut)
{
    int e = blockIdx.y >> 7;
    int mt = blockIdx.y & 127;
    int M = cnt[e];
    if (mt * 64 >= M) return;
    int rowBase = off[e] + mt * 64;
    int colBase = blockIdx.x * 64;
    const ushort* Bsrc = WtDn + ((size_t)e << 20);  // [d][h]

    __shared__ ushort As[64 * LROW];
    __shared__ ushort Bs[64 * LROW];

    int tid = threadIdx.x;
    int wave = tid >> 6, lane = tid & 63;
    int q = lane >> 4, r = lane & 15;
    int sRow = tid >> 2, sChunk = tid & 3;

    const ushort* aSrc = nullptr;
    if (mt * 64 + sRow < M) aSrc = Hbuf + (size_t)(rowBase + sRow) * 1024 + sChunk * 8;
    const ushort* bSrc = Bsrc + (size_t)(colBase + sRow) * 1024 + sChunk * 8;
    ushort* aDst = &As[sRow * LROW + sChunk * 8];
    ushort* bDst = &Bs[sRow * LROW + sChunk * 8];

    f32x4_t acc[4];
#pragma unroll
    for (int j = 0; j < 4; j++) { acc[j][0] = 0.f; acc[j][1] = 0.f; acc[j][2] = 0.f; acc[j][3] = 0.f; }

    for (int kk = 0; kk < 1024; kk += 32) {
        uint4 av = {0u, 0u, 0u, 0u};
        if (aSrc) av = *(const uint4*)(aSrc + kk);
        uint4 bv = *(const uint4*)(bSrc + kk);
        *(uint4*)aDst = av;
        *(uint4*)bDst = bv;
        __syncthreads();
        bf16x8_t af = *(const bf16x8_t*)(&As[(wave * 16 + r) * LROW + q * 8]);
#pragma unroll
        for (int j = 0; j < 4; j++) {
            bf16x8_t bv2 = *(const bf16x8_t*)(&Bs[(j * 16 + r) * LROW + q * 8]);
            acc[j] = __builtin_amdgcn_mfma_f32_16x16x32_bf16(af, bv2, acc[j], 0, 0, 0);
        }
        __syncthreads();
    }

    int rl0 = wave * 16 + q * 4;
#pragma unroll
    for (int j = 0; j < 4; j++) {
        int col = colBase + j * 16 + r;
#pragma unroll
        for (int i = 0; i < 4; i++) {
            int rl = rl0 + i;
            if (mt * 64 + rl < M) {
                int tok = pair_token[rowBase + rl];
                atomicAdd(&accOut[(size_t)tok * 1024 + col], acc[j][i]);
            }
        }
    }
}

// ---------------- finalize: out = acc + w0*bdn[e0] + w1*bdn[e1] ----------------
__global__ __launch_bounds__(256) void finalize_kernel(
    const float* __restrict__ accOut, const int2* __restrict__ tok_e,
    const float2* __restrict__ tok_w, const float* __restrict__ bdn,
    float* __restrict__ out)
{
    int t = blockIdx.x;
    int2 e = tok_e[t]; float2 w = tok_w[t];
    int c = threadIdx.x * 4;
    float4 a = *(const float4*)(accOut + (size_t)t * 1024 + c);
    float4 b0 = *(const float4*)(bdn + (size_t)e.x * 1024 + c);
    float4 b1 = *(const float4*)(bdn + (size_t)e.y * 1024 + c);
    float4 o;
    o.x = a.x + w.x * b0.x + w.y * b1.x;
    o.y = a.y + w.x * b0.y + w.y * b1.y;
    o.z = a.z + w.x * b0.z + w.y * b1.z;
    o.w = a.w + w.x * b0.w + w.y * b1.w;
    *(float4*)(out + (size_t)t * 1024 + c) = o;
}

extern "C" void kernel_launch(void* const* d_in, const int* in_sizes, int n_in,
                              void* d_out, int out_size, void* d_ws, size_t ws_size,
                              hipStream_t stream) {
    const float* x   = (const float*)d_in[0];
    const float* rw  = (const float*)d_in[1];
    const float* rb  = (const float*)d_in[2];
    const float* Wup = (const float*)d_in[3];
    const float* bup = (const float*)d_in[4];
    const float* Wdn = (const float*)d_in[5];
    const float* bdn = (const float*)d_in[6];
    float* out = (float*)d_out;

    char* ws = (char*)d_ws;
    int*    cnt   = (int*)(ws + 0);      // 8 ints
    int*    off   = (int*)(ws + 64);     // 8 ints
    int*    blockCnt = (int*)(ws + 128);         // 32*8 ints = 1 KB
    float*  blockSum = (float*)(ws + 1152);      // 32*8 floats = 1 KB
    int*    base     = (int*)(ws + 2176);        // 32*8 ints = 1 KB
    int2*   tok_e = (int2*)(ws + 4096);                 // 8192*8 = 64 KB
    float2* tok_w = (float2*)(ws + 4096 + 65536);       // 64 KB
    int*    pair_token = (int*)(ws + 4096 + 131072);    // 16384*4 = 64 KB
    float*  pair_w     = (float*)(ws + 4096 + 196608);  // 64 KB
    char* big = ws + 266240;
    ushort* Hbuf   = (ushort*)big;                        // 16384*1024*2 = 33554432
    float*  accOut = (float*)(big + 33554432);            // 8192*1024*4  = 33554432
    ushort* WtUp   = (ushort*)(big + 67108864);           // 16777216
    ushort* WtDn   = (ushort*)(big + 83886080);           // 16777216
    ushort* xb     = (ushort*)(big + 100663296);          // 8192*1024*2 = 16777216

    hipMemsetAsync(accOut, 0, (size_t)8192 * 1024 * sizeof(float), stream);

    cvt_x_kernel<<<8192, 256, 0, stream>>>(x, xb);
    transpose_kernel<<<dim3(16, 16, 16), 256, 0, stream>>>(Wup, Wdn, WtUp, WtDn);
    router_kernel<<<2048, 256, 0, stream>>>(x, rw, rb, tok_e, tok_w);
    count_kernel<<<32, 256, 0, stream>>>(tok_e, tok_w, blockCnt, blockSum);
    scan_kernel<<<1, 64, 0, stream>>>(blockCnt, blockSum, cnt, off, base, out + 8388608);
    assign_kernel<<<32, 256, 0, stream>>>(tok_e, tok_w, base, pair_token, pair_w);
    up_gemm<<<dim3(16, 1024), 256, 0, stream>>>(
        xb, WtUp, bup, cnt, off, pair_token, pair_w, Hbuf);
    down_gemm<<<dim3(16, 1024), 256, 0, stream>>>(
        Hbuf, WtDn, cnt, off, pair_token, accOut);
    finalize_kernel<<<8192, 256, 0, stream>>>(accOut, tok_e, tok_w, bdn, out);
}

// Round 4
// 357.110 us; speedup vs baseline: 1.9127x; 1.1319x over previous
//
#include <hip/hip_runtime.h>
#include <hip/hip_bf16.h>

typedef __attribute__((ext_vector_type(8))) short bf16x8_t;
typedef __attribute__((ext_vector_type(4))) float f32x4_t;

__device__ __forceinline__ void gld16(void* lds, const void* g) {
    __builtin_amdgcn_global_load_lds(
        (const __attribute__((address_space(1))) void*)g,
        (__attribute__((address_space(3))) void*)lds, 16, 0, 0);
}

__device__ inline unsigned short f2bf(float f) {
    __hip_bfloat16 h = __float2bfloat16(f);
    return *reinterpret_cast<unsigned short*>(&h);
}

// ---------- transpose+convert 1024x1024 fp32 matrices (16 of them) -> bf16 ----------
__global__ __launch_bounds__(256) void transpose_kernel(
    const float* __restrict__ Wup, const float* __restrict__ Wdn,
    ushort* __restrict__ WtUp, ushort* __restrict__ WtDn)
{
    int z = blockIdx.z;
    const float* src = (z < 8) ? (Wup + ((size_t)z << 20)) : (Wdn + ((size_t)(z - 8) << 20));
    ushort* dst      = (z < 8) ? (WtUp + ((size_t)z << 20)) : (WtDn + ((size_t)(z - 8) << 20));
    __shared__ float tile[64][65];
    int x0 = blockIdx.x * 64, y0 = blockIdx.y * 64;
    int row = threadIdx.x >> 4, colq = threadIdx.x & 15;
#pragma unroll
    for (int it = 0; it < 4; it++) {
        int r = row + it * 16;
        float4 v = *(const float4*)(src + (size_t)(y0 + r) * 1024 + x0 + colq * 4);
        tile[r][colq * 4 + 0] = v.x; tile[r][colq * 4 + 1] = v.y;
        tile[r][colq * 4 + 2] = v.z; tile[r][colq * 4 + 3] = v.w;
    }
    __syncthreads();
#pragma unroll
    for (int it = 0; it < 4; it++) {
        int r = row + it * 16;
        ushort4 o;
        o.x = f2bf(tile[colq * 4 + 0][r]); o.y = f2bf(tile[colq * 4 + 1][r]);
        o.z = f2bf(tile[colq * 4 + 2][r]); o.w = f2bf(tile[colq * 4 + 3][r]);
        *(ushort4*)(dst + (size_t)(x0 + r) * 1024 + y0 + colq * 4) = o;
    }
}

// ---------------- router: logits, top-2, softmax + fused x->bf16 ----------------
__global__ __launch_bounds__(256) void router_kernel(
    const float* __restrict__ x, const float* __restrict__ rw,
    const float* __restrict__ rb, ushort* __restrict__ xb,
    int2* __restrict__ tok_e, float2* __restrict__ tok_w)
{
    int wave = threadIdx.x >> 6, lane = threadIdx.x & 63;
    int t = blockIdx.x * 4 + wave;
    float4 xv[4];
#pragma unroll
    for (int i = 0; i < 4; i++)
        xv[i] = *(const float4*)(x + (size_t)t * 1024 + i * 256 + lane * 4);
#pragma unroll
    for (int i = 0; i < 4; i++) {
        ushort4 o;
        o.x = f2bf(xv[i].x); o.y = f2bf(xv[i].y); o.z = f2bf(xv[i].z); o.w = f2bf(xv[i].w);
        *(ushort4*)(xb + (size_t)t * 1024 + i * 256 + lane * 4) = o;
    }
    float logit[8];
#pragma unroll
    for (int e = 0; e < 8; e++) {
        float s = 0.f;
#pragma unroll
        for (int i = 0; i < 4; i++) {
            float4 wv = *(const float4*)(rw + e * 1024 + i * 256 + lane * 4);
            s += xv[i].x * wv.x + xv[i].y * wv.y + xv[i].z * wv.z + xv[i].w * wv.w;
        }
#pragma unroll
        for (int m = 32; m >= 1; m >>= 1) s += __shfl_xor(s, m, 64);
        logit[e] = s + rb[e];
    }
    int i0 = 0;
#pragma unroll
    for (int e = 1; e < 8; e++) if (logit[e] > logit[i0]) i0 = e;
    int i1 = -1;
#pragma unroll
    for (int e = 0; e < 8; e++) if (e != i0 && (i1 < 0 || logit[e] > logit[i1])) i1 = e;
    float ev = expf(logit[i1] - logit[i0]);
    float s = 1.f + ev;
    if (lane == 0) {
        tok_e[t] = make_int2(i0, i1);
        tok_w[t] = make_float2(1.f / s, ev / s);
    }
}

// ---------------- per-block histograms ----------------
__global__ __launch_bounds__(256) void count_kernel(
    const int2* __restrict__ tok_e, const float2* __restrict__ tok_w,
    int* __restrict__ blockCnt, float* __restrict__ blockSum)
{
    __shared__ int lcnt[8];
    __shared__ float lsum[8];
    int tid = threadIdx.x;
    if (tid < 8) { lcnt[tid] = 0; lsum[tid] = 0.f; }
    __syncthreads();
    int t = blockIdx.x * 256 + tid;
    int2 e = tok_e[t]; float2 w = tok_w[t];
    atomicAdd(&lcnt[e.x], 1); atomicAdd(&lsum[e.x], w.x);
    atomicAdd(&lcnt[e.y], 1); atomicAdd(&lsum[e.y], w.y);
    __syncthreads();
    if (tid < 8) {
        blockCnt[blockIdx.x * 8 + tid] = lcnt[tid];
        blockSum[blockIdx.x * 8 + tid] = lsum[tid];
    }
}

// ---------------- scan: offsets, per-block bases, tile table, aux loss ----------------
__global__ void scan_kernel(const int* __restrict__ blockCnt,
                            const float* __restrict__ blockSum,
                            int* __restrict__ cnt, int* __restrict__ off,
                            int* __restrict__ base, int* __restrict__ tileE,
                            int* __restrict__ tileRow, int* __restrict__ nTiles,
                            float* aux_out)
{
    if (threadIdx.x == 0) {
        int tot[8]; float sw[8];
        for (int e = 0; e < 8; e++) { tot[e] = 0; sw[e] = 0.f; }
        for (int b = 0; b < 32; b++)
            for (int e = 0; e < 8; e++) { tot[e] += blockCnt[b * 8 + e]; sw[e] += blockSum[b * 8 + e]; }
        int o = 0; float aux = 0.f; int nT = 0;
        for (int e = 0; e < 8; e++) {
            cnt[e] = tot[e]; off[e] = o;
            aux += (float)tot[e] * sw[e];
            int run = o;
            for (int b = 0; b < 32; b++) { base[b * 8 + e] = run; run += blockCnt[b * 8 + e]; }
            for (int tt = 0; tt * 128 < tot[e]; tt++) { tileE[nT] = e; tileRow[nT] = o + tt * 128; nT++; }
            o += tot[e];
        }
        *nTiles = nT;
        aux *= 8.0f / (8192.0f * 8192.0f);
        *aux_out = aux;
    }
}

// ---------------- slot assignment (LDS-local ranks) + inverse map ----------------
__global__ __launch_bounds__(256) void assign_kernel(
    const int2* __restrict__ tok_e, const float2* __restrict__ tok_w,
    const int* __restrict__ base, int* __restrict__ pair_token,
    float* __restrict__ pair_w, int2* __restrict__ tokSlot)
{
    __shared__ int lcnt[8];
    int tid = threadIdx.x;
    if (tid < 8) lcnt[tid] = 0;
    __syncthreads();
    int t = blockIdx.x * 256 + tid;
    int2 e = tok_e[t]; float2 w = tok_w[t];
    int r0 = atomicAdd(&lcnt[e.x], 1);
    int r1 = atomicAdd(&lcnt[e.y], 1);
    int s0 = base[blockIdx.x * 8 + e.x] + r0;
    int s1 = base[blockIdx.x * 8 + e.y] + r1;
    pair_token[s0] = t; pair_w[s0] = w.x;
    pair_token[s1] = t; pair_w[s1] = w.y;
    tokSlot[t] = make_int2(s0, s1);
}

// ---------------- up GEMM (128x128 tile, global_load_lds): H = gelu(Xg@Wup+b)*w ----------------
__global__ __launch_bounds__(256) void up_gemm(
    const ushort* __restrict__ xb, const ushort* __restrict__ WtUp,
    const float* __restrict__ bup,
    const int* __restrict__ cnt, const int* __restrict__ off,
    const int* __restrict__ nTiles, const int* __restrict__ tileE,
    const int* __restrict__ tileRow,
    const int* __restrict__ pair_token, const float* __restrict__ pair_w,
    const ushort* __restrict__ zeroPage, ushort* __restrict__ Hbuf)
{
    if ((int)blockIdx.y >= *nTiles) return;
    int e = tileE[blockIdx.y];
    int rowBase = tileRow[blockIdx.y];
    int expertEnd = off[e] + cnt[e];
    int colBase = blockIdx.x * 128;
    const ushort* Bsrc = WtUp + ((size_t)e << 20);

    __shared__ ushort As[128 * 32];
    __shared__ ushort Bs[128 * 32];

    int tid = threadIdx.x, w = tid >> 6, lane = tid & 63;
    int q = lane >> 4, r = lane & 15;
    int wm = w & 1, wn = w >> 1;

    int sr = lane >> 2;
    int cOff = (lane & 3) * 8;
    int rA0 = w * 32 + sr, rA1 = rA0 + 16;
    int g0 = rowBase + rA0, g1 = rowBase + rA1;

    const ushort* aP0 = (g0 < expertEnd) ? xb + (size_t)pair_token[g0] * 1024 + cOff : zeroPage + cOff;
    const ushort* aP1 = (g1 < expertEnd) ? xb + (size_t)pair_token[g1] * 1024 + cOff : zeroPage + cOff;
    const ushort* bP0 = Bsrc + (size_t)(colBase + rA0) * 1024 + cOff;
    const ushort* bP1 = bP0 + 16 * 1024;

    ushort* lA0 = &As[(w * 32) * 32];
    ushort* lA1 = &As[(w * 32 + 16) * 32];
    ushort* lB0 = &Bs[(w * 32) * 32];
    ushort* lB1 = &Bs[(w * 32 + 16) * 32];

    f32x4_t acc[4][4];
#pragma unroll
    for (int i = 0; i < 4; i++)
#pragma unroll
        for (int j = 0; j < 4; j++) { acc[i][j][0] = 0.f; acc[i][j][1] = 0.f; acc[i][j][2] = 0.f; acc[i][j][3] = 0.f; }

    for (int kk = 0; kk < 1024; kk += 32) {
        gld16(lA0, aP0 + kk);
        gld16(lA1, aP1 + kk);
        gld16(lB0, bP0 + kk);
        gld16(lB1, bP1 + kk);
        __syncthreads();
        bf16x8_t a[4], b[4];
#pragma unroll
        for (int i = 0; i < 4; i++) a[i] = *(const bf16x8_t*)&As[(wm * 64 + i * 16 + r) * 32 + q * 8];
#pragma unroll
        for (int j = 0; j < 4; j++) b[j] = *(const bf16x8_t*)&Bs[(wn * 64 + j * 16 + r) * 32 + q * 8];
#pragma unroll
        for (int i = 0; i < 4; i++)
#pragma unroll
            for (int j = 0; j < 4; j++)
                acc[i][j] = __builtin_amdgcn_mfma_f32_16x16x32_bf16(a[i], b[j], acc[i][j], 0, 0, 0);
        __syncthreads();
    }

#pragma unroll
    for (int j = 0; j < 4; j++) {
        int col = colBase + wn * 64 + j * 16 + r;
        float bias = bup[e * 1024 + col];
#pragma unroll
        for (int i = 0; i < 4; i++) {
#pragma unroll
            for (int reg = 0; reg < 4; reg++) {
                int gRow = rowBase + wm * 64 + i * 16 + q * 4 + reg;
                if (gRow < expertEnd) {
                    float h = acc[i][j][reg] + bias;
                    float g = 0.5f * h * (1.0f + erff(h * 0.70710678118654752f));
                    Hbuf[(size_t)gRow * 1024 + col] = f2bf(g * pair_w[gRow]);
                }
            }
        }
    }
}

// ---------------- down GEMM (128x128 tile): pairOut = H @ Wdn (bf16, no atomics) ----------------
__global__ __launch_bounds__(256) void down_gemm(
    const ushort* __restrict__ Hbuf, const ushort* __restrict__ WtDn,
    const int* __restrict__ cnt, const int* __restrict__ off,
    const int* __restrict__ nTiles, const int* __restrict__ tileE,
    const int* __restrict__ tileRow,
    const ushort* __restrict__ zeroPage, ushort* __restrict__ pairOut)
{
    if ((int)blockIdx.y >= *nTiles) return;
    int e = tileE[blockIdx.y];
    int rowBase = tileRow[blockIdx.y];
    int expertEnd = off[e] + cnt[e];
    int colBase = blockIdx.x * 128;
    const ushort* Bsrc = WtDn + ((size_t)e << 20);

    __shared__ ushort As[128 * 32];
    __shared__ ushort Bs[128 * 32];

    int tid = threadIdx.x, w = tid >> 6, lane = tid & 63;
    int q = lane >> 4, r = lane & 15;
    int wm = w & 1, wn = w >> 1;

    int sr = lane >> 2;
    int cOff = (lane & 3) * 8;
    int rA0 = w * 32 + sr, rA1 = rA0 + 16;
    int g0 = rowBase + rA0, g1 = rowBase + rA1;

    const ushort* aP0 = (g0 < expertEnd) ? Hbuf + (size_t)g0 * 1024 + cOff : zeroPage + cOff;
    const ushort* aP1 = (g1 < expertEnd) ? Hbuf + (size_t)g1 * 1024 + cOff : zeroPage + cOff;
    const ushort* bP0 = Bsrc + (size_t)(colBase + rA0) * 1024 + cOff;
    const ushort* bP1 = bP0 + 16 * 1024;

    ushort* lA0 = &As[(w * 32) * 32];
    ushort* lA1 = &As[(w * 32 + 16) * 32];
    ushort* lB0 = &Bs[(w * 32) * 32];
    ushort* lB1 = &Bs[(w * 32 + 16) * 32];

    f32x4_t acc[4][4];
#pragma unroll
    for (int i = 0; i < 4; i++)
#pragma unroll
        for (int j = 0; j < 4; j++) { acc[i][j][0] = 0.f; acc[i][j][1] = 0.f; acc[i][j][2] = 0.f; acc[i][j][3] = 0.f; }

    for (int kk = 0; kk < 1024; kk += 32) {
        gld16(lA0, aP0 + kk);
        gld16(lA1, aP1 + kk);
        gld16(lB0, bP0 + kk);
        gld16(lB1, bP1 + kk);
        __syncthreads();
        bf16x8_t a[4], b[4];
#pragma unroll
        for (int i = 0; i < 4; i++) a[i] = *(const bf16x8_t*)&As[(wm * 64 + i * 16 + r) * 32 + q * 8];
#pragma unroll
        for (int j = 0; j < 4; j++) b[j] = *(const bf16x8_t*)&Bs[(wn * 64 + j * 16 + r) * 32 + q * 8];
#pragma unroll
        for (int i = 0; i < 4; i++)
#pragma unroll
            for (int j = 0; j < 4; j++)
                acc[i][j] = __builtin_amdgcn_mfma_f32_16x16x32_bf16(a[i], b[j], acc[i][j], 0, 0, 0);
        __syncthreads();
    }

#pragma unroll
    for (int j = 0; j < 4; j++) {
        int col = colBase + wn * 64 + j * 16 + r;
#pragma unroll
        for (int i = 0; i < 4; i++) {
#pragma unroll
            for (int reg = 0; reg < 4; reg++) {
                int gRow = rowBase + wm * 64 + i * 16 + q * 4 + reg;
                if (gRow < expertEnd)
                    pairOut[(size_t)gRow * 1024 + col] = f2bf(acc[i][j][reg]);
            }
        }
    }
}

// ---------------- finalize: out[t] = pairOut[s0] + pairOut[s1] + w0*bdn[e0] + w1*bdn[e1] ----------------
__global__ __launch_bounds__(256) void finalize_kernel(
    const ushort* __restrict__ pairOut, const int2* __restrict__ tokSlot,
    const int2* __restrict__ tok_e, const float2* __restrict__ tok_w,
    const float* __restrict__ bdn, float* __restrict__ out)
{
    int t = blockIdx.x;
    int2 s = tokSlot[t]; int2 e = tok_e[t]; float2 w = tok_w[t];
    int c = threadIdx.x * 4;
    ushort4 p0 = *(const ushort4*)(pairOut + (size_t)s.x * 1024 + c);
    ushort4 p1 = *(const ushort4*)(pairOut + (size_t)s.y * 1024 + c);
    float4 b0 = *(const float4*)(bdn + (size_t)e.x * 1024 + c);
    float4 b1 = *(const float4*)(bdn + (size_t)e.y * 1024 + c);
    __hip_bfloat16* h0 = (__hip_bfloat16*)&p0;
    __hip_bfloat16* h1 = (__hip_bfloat16*)&p1;
    float4 o;
    o.x = __bfloat162float(h0[0]) + __bfloat162float(h1[0]) + w.x * b0.x + w.y * b1.x;
    o.y = __bfloat162float(h0[1]) + __bfloat162float(h1[1]) + w.x * b0.y + w.y * b1.y;
    o.z = __bfloat162float(h0[2]) + __bfloat162float(h1[2]) + w.x * b0.z + w.y * b1.z;
    o.w = __bfloat162float(h0[3]) + __bfloat162float(h1[3]) + w.x * b0.w + w.y * b1.w;
    *(float4*)(out + (size_t)t * 1024 + c) = o;
}

extern "C" void kernel_launch(void* const* d_in, const int* in_sizes, int n_in,
                              void* d_out, int out_size, void* d_ws, size_t ws_size,
                              hipStream_t stream) {
    const float* x   = (const float*)d_in[0];
    const float* rw  = (const float*)d_in[1];
    const float* rb  = (const float*)d_in[2];
    const float* Wup = (const float*)d_in[3];
    const float* bup = (const float*)d_in[4];
    const float* Wdn = (const float*)d_in[5];
    const float* bdn = (const float*)d_in[6];
    float* out = (float*)d_out;

    char* ws = (char*)d_ws;
    int*    cnt      = (int*)(ws + 0);
    int*    off      = (int*)(ws + 64);
    int*    nTiles   = (int*)(ws + 128);
    int*    blockCnt = (int*)(ws + 256);    // 1 KB
    float*  blockSum = (float*)(ws + 1536); // 1 KB
    int*    base     = (int*)(ws + 2816);   // 1 KB
    int*    tileE    = (int*)(ws + 4096);   // 640 B
    int*    tileRow  = (int*)(ws + 4736);   // 640 B
    ushort* zeroPage = (ushort*)(ws + 8192);            // 4 KB
    int2*   tok_e    = (int2*)(ws + 12288);             // 64 KB
    float2* tok_w    = (float2*)(ws + 77824);           // 64 KB
    int2*   tokSlot  = (int2*)(ws + 143360);            // 64 KB
    int*    pair_token = (int*)(ws + 208896);           // 64 KB
    float*  pair_w     = (float*)(ws + 274432);         // 64 KB
    char* big = ws + 1048576;
    ushort* Hbuf    = (ushort*)big;                     // 16384*1024*2 = 33554432
    ushort* pairOut = (ushort*)(big + 33554432);        // 16384*1024*2 = 33554432
    ushort* WtUp    = (ushort*)(big + 67108864);        // 16777216
    ushort* WtDn    = (ushort*)(big + 83886080);        // 16777216
    ushort* xb      = (ushort*)(big + 100663296);       // 16777216

    hipMemsetAsync(zeroPage, 0, 4096, stream);

    transpose_kernel<<<dim3(16, 16, 16), 256, 0, stream>>>(Wup, Wdn, WtUp, WtDn);
    router_kernel<<<2048, 256, 0, stream>>>(x, rw, rb, xb, tok_e, tok_w);
    count_kernel<<<32, 256, 0, stream>>>(tok_e, tok_w, blockCnt, blockSum);
    scan_kernel<<<1, 64, 0, stream>>>(blockCnt, blockSum, cnt, off, base,
                                      tileE, tileRow, nTiles, out + 8388608);
    assign_kernel<<<32, 256, 0, stream>>>(tok_e, tok_w, base, pair_token, pair_w, tokSlot);
    up_gemm<<<dim3(8, 136), 256, 0, stream>>>(
        xb, WtUp, bup, cnt, off, nTiles, tileE, tileRow, pair_token, pair_w, zeroPage, Hbuf);
    down_gemm<<<dim3(8, 136), 256, 0, stream>>>(
        Hbuf, WtDn, cnt, off, nTiles, tileE, tileRow, zeroPage, pairOut);
    finalize_kernel<<<8192, 256, 0, stream>>>(pairOut, tokSlot, tok_e, tok_w, bdn, out);
}

// Round 5
// 344.418 us; speedup vs baseline: 1.9832x; 1.0368x over previous
//
#include <hip/hip_runtime.h>
#include <hip/hip_bf16.h>

typedef __attribute__((ext_vector_type(8))) short bf16x8_t;
typedef __attribute__((ext_vector_type(4))) float f32x4_t;

__device__ __forceinline__ void gld16(void* lds, const void* g) {
    __builtin_amdgcn_global_load_lds(
        (const __attribute__((address_space(1))) void*)g,
        (__attribute__((address_space(3))) void*)lds, 16, 0, 0);
}

__device__ inline unsigned short f2bf(float f) {
    __hip_bfloat16 h = __float2bfloat16(f);
    return *reinterpret_cast<unsigned short*>(&h);
}

// ---------- transpose+convert 1024x1024 fp32 matrices (16 of them) -> bf16 ----------
__global__ __launch_bounds__(256) void transpose_kernel(
    const float* __restrict__ Wup, const float* __restrict__ Wdn,
    ushort* __restrict__ WtUp, ushort* __restrict__ WtDn)
{
    int z = blockIdx.z;
    const float* src = (z < 8) ? (Wup + ((size_t)z << 20)) : (Wdn + ((size_t)(z - 8) << 20));
    ushort* dst      = (z < 8) ? (WtUp + ((size_t)z << 20)) : (WtDn + ((size_t)(z - 8) << 20));
    __shared__ float tile[64][65];
    int x0 = blockIdx.x * 64, y0 = blockIdx.y * 64;
    int row = threadIdx.x >> 4, colq = threadIdx.x & 15;
#pragma unroll
    for (int it = 0; it < 4; it++) {
        int r = row + it * 16;
        float4 v = *(const float4*)(src + (size_t)(y0 + r) * 1024 + x0 + colq * 4);
        tile[r][colq * 4 + 0] = v.x; tile[r][colq * 4 + 1] = v.y;
        tile[r][colq * 4 + 2] = v.z; tile[r][colq * 4 + 3] = v.w;
    }
    __syncthreads();
#pragma unroll
    for (int it = 0; it < 4; it++) {
        int r = row + it * 16;
        ushort4 o;
        o.x = f2bf(tile[colq * 4 + 0][r]); o.y = f2bf(tile[colq * 4 + 1][r]);
        o.z = f2bf(tile[colq * 4 + 2][r]); o.w = f2bf(tile[colq * 4 + 3][r]);
        *(ushort4*)(dst + (size_t)(x0 + r) * 1024 + y0 + colq * 4) = o;
    }
}

// ---------------- router: logits, top-2, softmax + fused x->bf16 ----------------
__global__ __launch_bounds__(256) void router_kernel(
    const float* __restrict__ x, const float* __restrict__ rw,
    const float* __restrict__ rb, ushort* __restrict__ xb,
    int2* __restrict__ tok_e, float2* __restrict__ tok_w)
{
    int wave = threadIdx.x >> 6, lane = threadIdx.x & 63;
    int t = blockIdx.x * 4 + wave;
    float4 xv[4];
#pragma unroll
    for (int i = 0; i < 4; i++)
        xv[i] = *(const float4*)(x + (size_t)t * 1024 + i * 256 + lane * 4);
#pragma unroll
    for (int i = 0; i < 4; i++) {
        ushort4 o;
        o.x = f2bf(xv[i].x); o.y = f2bf(xv[i].y); o.z = f2bf(xv[i].z); o.w = f2bf(xv[i].w);
        *(ushort4*)(xb + (size_t)t * 1024 + i * 256 + lane * 4) = o;
    }
    float logit[8];
#pragma unroll
    for (int e = 0; e < 8; e++) {
        float s = 0.f;
#pragma unroll
        for (int i = 0; i < 4; i++) {
            float4 wv = *(const float4*)(rw + e * 1024 + i * 256 + lane * 4);
            s += xv[i].x * wv.x + xv[i].y * wv.y + xv[i].z * wv.z + xv[i].w * wv.w;
        }
#pragma unroll
        for (int m = 32; m >= 1; m >>= 1) s += __shfl_xor(s, m, 64);
        logit[e] = s + rb[e];
    }
    int i0 = 0;
#pragma unroll
    for (int e = 1; e < 8; e++) if (logit[e] > logit[i0]) i0 = e;
    int i1 = -1;
#pragma unroll
    for (int e = 0; e < 8; e++) if (e != i0 && (i1 < 0 || logit[e] > logit[i1])) i1 = e;
    float ev = expf(logit[i1] - logit[i0]);
    float s = 1.f + ev;
    if (lane == 0) {
        tok_e[t] = make_int2(i0, i1);
        tok_w[t] = make_float2(1.f / s, ev / s);
    }
}

// ---------------- per-block histograms ----------------
__global__ __launch_bounds__(256) void count_kernel(
    const int2* __restrict__ tok_e, const float2* __restrict__ tok_w,
    int* __restrict__ blockCnt, float* __restrict__ blockSum)
{
    __shared__ int lcnt[8];
    __shared__ float lsum[8];
    int tid = threadIdx.x;
    if (tid < 8) { lcnt[tid] = 0; lsum[tid] = 0.f; }
    __syncthreads();
    int t = blockIdx.x * 256 + tid;
    int2 e = tok_e[t]; float2 w = tok_w[t];
    atomicAdd(&lcnt[e.x], 1); atomicAdd(&lsum[e.x], w.x);
    atomicAdd(&lcnt[e.y], 1); atomicAdd(&lsum[e.y], w.y);
    __syncthreads();
    if (tid < 8) {
        blockCnt[blockIdx.x * 8 + tid] = lcnt[tid];
        blockSum[blockIdx.x * 8 + tid] = lsum[tid];
    }
}

// ---------------- scan: offsets, per-block bases, tile table, aux loss ----------------
__global__ void scan_kernel(const int* __restrict__ blockCnt,
                            const float* __restrict__ blockSum,
                            int* __restrict__ cnt, int* __restrict__ off,
                            int* __restrict__ base, int* __restrict__ tileE,
                            int* __restrict__ tileRow, int* __restrict__ nTiles,
                            float* aux_out)
{
    if (threadIdx.x == 0) {
        int tot[8]; float sw[8];
        for (int e = 0; e < 8; e++) { tot[e] = 0; sw[e] = 0.f; }
        for (int b = 0; b < 32; b++)
            for (int e = 0; e < 8; e++) { tot[e] += blockCnt[b * 8 + e]; sw[e] += blockSum[b * 8 + e]; }
        int o = 0; float aux = 0.f; int nT = 0;
        for (int e = 0; e < 8; e++) {
            cnt[e] = tot[e]; off[e] = o;
            aux += (float)tot[e] * sw[e];
            int run = o;
            for (int b = 0; b < 32; b++) { base[b * 8 + e] = run; run += blockCnt[b * 8 + e]; }
            for (int tt = 0; tt * 128 < tot[e]; tt++) { tileE[nT] = e; tileRow[nT] = o + tt * 128; nT++; }
            o += tot[e];
        }
        *nTiles = nT;
        aux *= 8.0f / (8192.0f * 8192.0f);
        *aux_out = aux;
    }
}

// ---------------- slot assignment (LDS-local ranks) + inverse map ----------------
__global__ __launch_bounds__(256) void assign_kernel(
    const int2* __restrict__ tok_e, const float2* __restrict__ tok_w,
    const int* __restrict__ base, int* __restrict__ pair_token,
    float* __restrict__ pair_w, int2* __restrict__ tokSlot)
{
    __shared__ int lcnt[8];
    int tid = threadIdx.x;
    if (tid < 8) lcnt[tid] = 0;
    __syncthreads();
    int t = blockIdx.x * 256 + tid;
    int2 e = tok_e[t]; float2 w = tok_w[t];
    int r0 = atomicAdd(&lcnt[e.x], 1);
    int r1 = atomicAdd(&lcnt[e.y], 1);
    int s0 = base[blockIdx.x * 8 + e.x] + r0;
    int s1 = base[blockIdx.x * 8 + e.y] + r1;
    pair_token[s0] = t; pair_w[s0] = w.x;
    pair_token[s1] = t; pair_w[s1] = w.y;
    tokSlot[t] = make_int2(s0, s1);
}

// -------- up GEMM (128x128 tile, 512 thr / 8 waves): H = gelu(Xg@Wup+b)*w --------
__global__ __launch_bounds__(512, 4) void up_gemm(
    const ushort* __restrict__ xb, const ushort* __restrict__ WtUp,
    const float* __restrict__ bup,
    const int* __restrict__ cnt, const int* __restrict__ off,
    const int* __restrict__ nTiles, const int* __restrict__ tileE,
    const int* __restrict__ tileRow,
    const int* __restrict__ pair_token, const float* __restrict__ pair_w,
    const ushort* __restrict__ zeroPage, ushort* __restrict__ Hbuf)
{
    if ((int)blockIdx.y >= *nTiles) return;
    int e = tileE[blockIdx.y];
    int rowBase = tileRow[blockIdx.y];
    int expertEnd = off[e] + cnt[e];
    int colBase = blockIdx.x * 128;
    const ushort* Bsrc = WtUp + ((size_t)e << 20);

    __shared__ ushort As[128 * 32];
    __shared__ ushort Bs[128 * 32];

    int tid = threadIdx.x, w = tid >> 6, lane = tid & 63;
    int q = lane >> 4, r = lane & 15;
    int wm = w & 3, wn = w >> 2;

    int sr = lane >> 2;
    int cOff = (lane & 3) * 8;
    int rA = w * 16 + sr;               // 0..127, each wave stages 16 rows
    int gA = rowBase + rA;

    const ushort* aP = (gA < expertEnd) ? xb + (size_t)pair_token[gA] * 1024 + cOff : zeroPage + cOff;
    const ushort* bP = Bsrc + (size_t)(colBase + rA) * 1024 + cOff;

    ushort* lA = &As[(w * 16) * 32];
    ushort* lB = &Bs[(w * 16) * 32];

    f32x4_t acc[2][4];
#pragma unroll
    for (int i = 0; i < 2; i++)
#pragma unroll
        for (int j = 0; j < 4; j++) { acc[i][j][0] = 0.f; acc[i][j][1] = 0.f; acc[i][j][2] = 0.f; acc[i][j][3] = 0.f; }

    for (int kk = 0; kk < 1024; kk += 32) {
        gld16(lA, aP + kk);
        gld16(lB, bP + kk);
        __syncthreads();
        bf16x8_t a[2], b[4];
#pragma unroll
        for (int i = 0; i < 2; i++) a[i] = *(const bf16x8_t*)&As[(wm * 32 + i * 16 + r) * 32 + q * 8];
#pragma unroll
        for (int j = 0; j < 4; j++) b[j] = *(const bf16x8_t*)&Bs[(wn * 64 + j * 16 + r) * 32 + q * 8];
#pragma unroll
        for (int i = 0; i < 2; i++)
#pragma unroll
            for (int j = 0; j < 4; j++)
                acc[i][j] = __builtin_amdgcn_mfma_f32_16x16x32_bf16(a[i], b[j], acc[i][j], 0, 0, 0);
        __syncthreads();
    }

#pragma unroll
    for (int j = 0; j < 4; j++) {
        int col = colBase + wn * 64 + j * 16 + r;
        float bias = bup[e * 1024 + col];
#pragma unroll
        for (int i = 0; i < 2; i++) {
#pragma unroll
            for (int reg = 0; reg < 4; reg++) {
                int gRow = rowBase + wm * 32 + i * 16 + q * 4 + reg;
                if (gRow < expertEnd) {
                    float h = acc[i][j][reg] + bias;
                    float g = 0.5f * h * (1.0f + erff(h * 0.70710678118654752f));
                    Hbuf[(size_t)gRow * 1024 + col] = f2bf(g * pair_w[gRow]);
                }
            }
        }
    }
}

// -------- down GEMM (128x128 tile, 512 thr): pairOut = H @ Wdn (bf16, no atomics) --------
__global__ __launch_bounds__(512, 4) void down_gemm(
    const ushort* __restrict__ Hbuf, const ushort* __restrict__ WtDn,
    const int* __restrict__ cnt, const int* __restrict__ off,
    const int* __restrict__ nTiles, const int* __restrict__ tileE,
    const int* __restrict__ tileRow,
    const ushort* __restrict__ zeroPage, ushort* __restrict__ pairOut)
{
    if ((int)blockIdx.y >= *nTiles) return;
    int e = tileE[blockIdx.y];
    int rowBase = tileRow[blockIdx.y];
    int expertEnd = off[e] + cnt[e];
    int colBase = blockIdx.x * 128;
    const ushort* Bsrc = WtDn + ((size_t)e << 20);

    __shared__ ushort As[128 * 32];
    __shared__ ushort Bs[128 * 32];

    int tid = threadIdx.x, w = tid >> 6, lane = tid & 63;
    int q = lane >> 4, r = lane & 15;
    int wm = w & 3, wn = w >> 2;

    int sr = lane >> 2;
    int cOff = (lane & 3) * 8;
    int rA = w * 16 + sr;
    int gA = rowBase + rA;

    const ushort* aP = (gA < expertEnd) ? Hbuf + (size_t)gA * 1024 + cOff : zeroPage + cOff;
    const ushort* bP = Bsrc + (size_t)(colBase + rA) * 1024 + cOff;

    ushort* lA = &As[(w * 16) * 32];
    ushort* lB = &Bs[(w * 16) * 32];

    f32x4_t acc[2][4];
#pragma unroll
    for (int i = 0; i < 2; i++)
#pragma unroll
        for (int j = 0; j < 4; j++) { acc[i][j][0] = 0.f; acc[i][j][1] = 0.f; acc[i][j][2] = 0.f; acc[i][j][3] = 0.f; }

    for (int kk = 0; kk < 1024; kk += 32) {
        gld16(lA, aP + kk);
        gld16(lB, bP + kk);
        __syncthreads();
        bf16x8_t a[2], b[4];
#pragma unroll
        for (int i = 0; i < 2; i++) a[i] = *(const bf16x8_t*)&As[(wm * 32 + i * 16 + r) * 32 + q * 8];
#pragma unroll
        for (int j = 0; j < 4; j++) b[j] = *(const bf16x8_t*)&Bs[(wn * 64 + j * 16 + r) * 32 + q * 8];
#pragma unroll
        for (int i = 0; i < 2; i++)
#pragma unroll
            for (int j = 0; j < 4; j++)
                acc[i][j] = __builtin_amdgcn_mfma_f32_16x16x32_bf16(a[i], b[j], acc[i][j], 0, 0, 0);
        __syncthreads();
    }

#pragma unroll
    for (int j = 0; j < 4; j++) {
        int col = colBase + wn * 64 + j * 16 + r;
#pragma unroll
        for (int i = 0; i < 2; i++) {
#pragma unroll
            for (int reg = 0; reg < 4; reg++) {
                int gRow = rowBase + wm * 32 + i * 16 + q * 4 + reg;
                if (gRow < expertEnd)
                    pairOut[(size_t)gRow * 1024 + col] = f2bf(acc[i][j][reg]);
            }
        }
    }
}

// ---------------- finalize: out[t] = pairOut[s0] + pairOut[s1] + w0*bdn[e0] + w1*bdn[e1] ----------------
__global__ __launch_bounds__(256) void finalize_kernel(
    const ushort* __restrict__ pairOut, const int2* __restrict__ tokSlot,
    const int2* __restrict__ tok_e, const float2* __restrict__ tok_w,
    const float* __restrict__ bdn, float* __restrict__ out)
{
    int t = blockIdx.x;
    int2 s = tokSlot[t]; int2 e = tok_e[t]; float2 w = tok_w[t];
    int c = threadIdx.x * 4;
    ushort4 p0 = *(const ushort4*)(pairOut + (size_t)s.x * 1024 + c);
    ushort4 p1 = *(const ushort4*)(pairOut + (size_t)s.y * 1024 + c);
    float4 b0 = *(const float4*)(bdn + (size_t)e.x * 1024 + c);
    float4 b1 = *(const float4*)(bdn + (size_t)e.y * 1024 + c);
    __hip_bfloat16* h0 = (__hip_bfloat16*)&p0;
    __hip_bfloat16* h1 = (__hip_bfloat16*)&p1;
    float4 o;
    o.x = __bfloat162float(h0[0]) + __bfloat162float(h1[0]) + w.x * b0.x + w.y * b1.x;
    o.y = __bfloat162float(h0[1]) + __bfloat162float(h1[1]) + w.x * b0.y + w.y * b1.y;
    o.z = __bfloat162float(h0[2]) + __bfloat162float(h1[2]) + w.x * b0.z + w.y * b1.z;
    o.w = __bfloat162float(h0[3]) + __bfloat162float(h1[3]) + w.x * b0.w + w.y * b1.w;
    *(float4*)(out + (size_t)t * 1024 + c) = o;
}

extern "C" void kernel_launch(void* const* d_in, const int* in_sizes, int n_in,
                              void* d_out, int out_size, void* d_ws, size_t ws_size,
                              hipStream_t stream) {
    const float* x   = (const float*)d_in[0];
    const float* rw  = (const float*)d_in[1];
    const float* rb  = (const float*)d_in[2];
    const float* Wup = (const float*)d_in[3];
    const float* bup = (const float*)d_in[4];
    const float* Wdn = (const float*)d_in[5];
    const float* bdn = (const float*)d_in[6];
    float* out = (float*)d_out;

    char* ws = (char*)d_ws;
    int*    cnt      = (int*)(ws + 0);
    int*    off      = (int*)(ws + 64);
    int*    nTiles   = (int*)(ws + 128);
    int*    blockCnt = (int*)(ws + 256);    // 1 KB
    float*  blockSum = (float*)(ws + 1536); // 1 KB
    int*    base     = (int*)(ws + 2816);   // 1 KB
    int*    tileE    = (int*)(ws + 4096);   // 640 B
    int*    tileRow  = (int*)(ws + 4736);   // 640 B
    ushort* zeroPage = (ushort*)(ws + 8192);            // 4 KB
    int2*   tok_e    = (int2*)(ws + 12288);             // 64 KB
    float2* tok_w    = (float2*)(ws + 77824);           // 64 KB
    int2*   tokSlot  = (int2*)(ws + 143360);            // 64 KB
    int*    pair_token = (int*)(ws + 208896);           // 64 KB
    float*  pair_w     = (float*)(ws + 274432);         // 64 KB
    char* big = ws + 1048576;
    ushort* Hbuf    = (ushort*)big;                     // 16384*1024*2 = 33554432
    ushort* pairOut = (ushort*)(big + 33554432);        // 16384*1024*2 = 33554432
    ushort* WtUp    = (ushort*)(big + 67108864);        // 16777216
    ushort* WtDn    = (ushort*)(big + 83886080);        // 16777216
    ushort* xb      = (ushort*)(big + 100663296);       // 16777216

    hipMemsetAsync(zeroPage, 0, 4096, stream);

    transpose_kernel<<<dim3(16, 16, 16), 256, 0, stream>>>(Wup, Wdn, WtUp, WtDn);
    router_kernel<<<2048, 256, 0, stream>>>(x, rw, rb, xb, tok_e, tok_w);
    count_kernel<<<32, 256, 0, stream>>>(tok_e, tok_w, blockCnt, blockSum);
    scan_kernel<<<1, 64, 0, stream>>>(blockCnt, blockSum, cnt, off, base,
                                      tileE, tileRow, nTiles, out + 8388608);
    assign_kernel<<<32, 256, 0, stream>>>(tok_e, tok_w, base, pair_token, pair_w, tokSlot);
    up_gemm<<<dim3(8, 136), 512, 0, stream>>>(
        xb, WtUp, bup, cnt, off, nTiles, tileE, tileRow, pair_token, pair_w, zeroPage, Hbuf);
    down_gemm<<<dim3(8, 136), 512, 0, stream>>>(
        Hbuf, WtDn, cnt, off, nTiles, tileE, tileRow, zeroPage, pairOut);
    finalize_kernel<<<8192, 256, 0, stream>>>(pairOut, tokSlot, tok_e, tok_w, bdn, out);
}